// Round 7
// baseline (47.088 us; speedup 1.0000x reference)
//
#include <hip/hip_runtime.h>
#include <math.h>

#define BB 2
#define PP 4096
#define CC 64
#define SZ 128
#define KK 8

// radius = 1.5/128*2 = 0.0234375 (exact); r^2 = 9*2^-14 (exact)
#define R2f 0.00054931640625f
#define MAXL 96           // per-tile list cap (mean ~43, +8 sigma safe)
#define NTILE 512         // B * 16 * 16
#define FP 68             // F row stride (pad: 16B-aligned, bank-spread)

typedef unsigned long long u64;
#define EMPTYK (~0ull)

// ---- Kernel 1: fused point->tile binning + src transpose [C][P]->[P][C] ----
__global__ __launch_bounds__(256) void prep_kernel(const float* __restrict__ pts,
                                                   const float* __restrict__ src,
                                                   float* __restrict__ srcT,
                                                   int* __restrict__ cnt,
                                                   int* __restrict__ lists) {
    const int tidb = threadIdx.x;
    const int blk  = blockIdx.x;               // 0..127

    // ---- bin: one thread per point (threads 0..8191)
    const int t = blk * 256 + tidb;
    if (t < BB * PP) {
        const int b = t >> 12;
        const int p = t & (PP - 1);
        const float px = pts[t * 3 + 0];
        const float py = pts[t * 3 + 1];
        const float pz = pts[t * 3 + 2];
        if (pz > 0.0f) {
            // pixel-space center of the point (hit at w where gx(w) ~ -px)
            const float u = (1.0f + px) * 64.0f - 0.5f;
            const float v = (1.0f + py) * 64.0f - 0.5f;
            // reach: 1.5px radius + 1px bg ring + slack -> 2.6px; span 5.2 < 8
            const int tx0 = max(0,  (int)floorf((u - 2.6f) * 0.125f));
            const int tx1 = min(15, (int)floorf((u + 2.6f) * 0.125f));
            const int ty0 = max(0,  (int)floorf((v - 2.6f) * 0.125f));
            const int ty1 = min(15, (int)floorf((v + 2.6f) * 0.125f));
            for (int ty = ty0; ty <= ty1; ++ty)
                for (int tx = tx0; tx <= tx1; ++tx) {
                    const int tile = (b << 8) | (ty << 4) | tx;
                    const int pos = atomicAdd(cnt + tile, 1);
                    if (pos < MAXL) lists[tile * MAXL + pos] = p;
                }
        }
    }

    // ---- transpose: block -> (batch b2, 64-point group j); LDS 64x65
    __shared__ float lt[64][65];
    const int b2 = blk >> 6;
    const int p0 = (blk & 63) << 6;
    const int rr = tidb >> 6;                  // 0..3
    const int cc = tidb & 63;
#pragma unroll
    for (int k = 0; k < 16; ++k) {
        const int c = k * 4 + rr;
        lt[c][cc] = src[(size_t)((b2 * CC + c) << 12 | (p0 + cc))];
    }
    __syncthreads();
#pragma unroll
    for (int k = 0; k < 16; ++k) {
        const int pl = k * 4 + rr;
        srcT[(size_t)(((b2 << 12) | (p0 + pl)) << 6 | cc)] = lt[cc][pl];
    }
}

// ---- Kernel 2: per-tile select + weights + composite + bg (no scan) -------
__global__ __launch_bounds__(256) void mega_kernel(const float* __restrict__ pts,
                                                   const float* __restrict__ srcT,
                                                   const int* __restrict__ cnt,
                                                   const int* __restrict__ lists,
                                                   float* __restrict__ out,
                                                   float* __restrict__ bgout) {
    const int tidb = threadIdx.x;
    const int bid  = blockIdx.x;               // 0..511
    const int b    = bid >> 8;
    const int tile = bid & 255;
    const int ty = tile >> 4, tx = tile & 15;
    const int w0 = tx * 8, h0 = ty * 8;

    __shared__ float sx[MAXL], sy[MAXL], sz[MAXL];
    __shared__ int   si[MAXL];
    __shared__ float F[MAXL][FP];              // staged features [listpos][ch]
    __shared__ float wgt[KK][64];
    __shared__ int   wlp[KK][64];
    __shared__ int   nsl[64];
    __shared__ float covl[100];                // 10x10 patch, 1 = empty pixel

    int L = cnt[bid];
    L = min(L, MAXL);

    // ---- stage list coords (scattered, small) + features (coalesced)
    if (tidb < L) {
        const int p = lists[bid * MAXL + tidb];
        si[tidb] = p;
        const float* q = pts + (size_t)((b << 12) + p) * 3;
        sx[tidb] = q[0]; sy[tidb] = q[1]; sz[tidb] = q[2];
    }
    for (int item = tidb; item < L * 16; item += 256) {
        const int jj = item >> 4;
        const int c4 = (item & 15) << 2;
        const int p  = lists[bid * MAXL + jj];
        const float4 v = *(const float4*)&srcT[(size_t)(((b << 12) + p) << 6) + c4];
        *(float4*)&F[jj][c4] = v;
    }
    __syncthreads();

    // ---- K-buffer: lane = (quarter q, pixel pxl); wave w owns px 16w..16w+15
    const int wv  = tidb >> 6;
    const int l   = tidb & 63;
    const int q   = l >> 4;
    const int pxl = l & 15;
    const int px  = wv * 16 + pxl;
    const int row = px >> 3, col = px & 7;
    const float gx = 1.0f - (2 * (w0 + col) + 1) * (1.0f / 128.0f);
    const float gy = 1.0f - (2 * (h0 + row) + 1) * (1.0f / 128.0f);

    u64 key[KK]; float kd2[KK]; int kps[KK];
#pragma unroll
    for (int s = 0; s < KK; ++s) { key[s] = EMPTYK; kd2[s] = 0.0f; kps[s] = 0; }

    const int niter = (L + 3) >> 2;
    for (int i = 0; i < niter; ++i) {
        const int pos = 4 * i + q;             // strided quarter
        if (pos < L) {
            const float dx = __fadd_rn(gx, sx[pos]);   // ref: gx - (-px)
            const float dy = __fadd_rn(gy, sy[pos]);
            const float d2 = __fadd_rn(__fmul_rn(dx, dx), __fmul_rn(dy, dy));
            const float z  = sz[pos];
            if (d2 < R2f && z > 0.0f) {
                u64   kn = ((u64)__float_as_uint(z) << 32) | (unsigned)si[pos];
                float dn = d2;
                int   pn = pos;
#pragma unroll
                for (int s = 0; s < KK; ++s) {
                    if (kn < key[s]) {         // (z, idx) strict order: stable
                        u64   tk = key[s]; key[s] = kn; kn = tk;
                        float td = kd2[s]; kd2[s] = dn; dn = td;
                        int   tp = kps[s]; kps[s] = pn; pn = tp;
                    }
                }
            }
        }
    }

    // ---- merge quarters: butterfly xor 32 then 16 (snapshot, then insert)
#pragma unroll
    for (int dist = 32; dist >= 16; dist >>= 1) {
        u64 rk[KK]; float rd[KK]; int rp[KK];
#pragma unroll
        for (int s = 0; s < KK; ++s) {
            rk[s] = __shfl_xor(key[s], dist, 64);
            rd[s] = __shfl_xor(kd2[s], dist, 64);
            rp[s] = __shfl_xor(kps[s], dist, 64);
        }
#pragma unroll
        for (int s = 0; s < KK; ++s) {
            if (rk[s] != EMPTYK) {
                u64 kn = rk[s]; float dn = rd[s]; int pn = rp[s];
#pragma unroll
                for (int s2 = 0; s2 < KK; ++s2) {
                    if (kn < key[s2]) {
                        u64   tk = key[s2]; key[s2] = kn; kn = tk;
                        float td = kd2[s2]; kd2[s2] = dn; dn = td;
                        int   tp = kps[s2]; kps[s2] = pn; pn = tp;
                    }
                }
            }
        }
    }

    // ---- epilogue: lanes 0..15 own px; lanes 48..56 do bg ring coverage
    if (l < 16) {
        int ns = 0;
        float T = 1.0f;
#pragma unroll
        for (int s = 0; s < KK; ++s) {
            if (key[s] != EMPTYK) {
                ns = s + 1;
                float dn = kd2[s] / R2f;
                dn = fminf(fmaxf(dn, 0.001f), 1.0f);
                const float a = 1.0f - sqrtf(dn);
                wgt[s][px] = a * T;
                T = T * (1.0f - a);
                wlp[s][px] = kps[s];
            }
        }
        nsl[px] = ns;
        covl[(row + 1) * 10 + (col + 1)] = ns ? 0.0f : 1.0f;
    } else if (l >= 48 && l < 57) {
        const int r = wv * 9 + (l - 48);       // 36 ring cells over 4 waves
        int pi, pj;
        if      (r < 10) { pi = 0;      pj = r;      }
        else if (r < 20) { pi = 9;      pj = r - 10; }
        else if (r < 28) { pi = r - 19; pj = 0;      }
        else             { pi = r - 27; pj = 9;      }
        const int hh = h0 - 1 + pi, ww = w0 - 1 + pj;
        float cv = 0.0f;                       // OOB -> not background
        if (hh >= 0 && hh < SZ && ww >= 0 && ww < SZ) {
            const float gx2 = 1.0f - (2 * ww + 1) * (1.0f / 128.0f);
            const float gy2 = 1.0f - (2 * hh + 1) * (1.0f / 128.0f);
            int hit = 0;
            for (int pos = 0; pos < L && !hit; ++pos) {
                const float dx = __fadd_rn(gx2, sx[pos]);
                const float dy = __fadd_rn(gy2, sy[pos]);
                const float d2 = __fadd_rn(__fmul_rn(dx, dx), __fmul_rn(dy, dy));
                if (d2 < R2f && sz[pos] > 0.0f) hit = 1;
            }
            cv = hit ? 0.0f : 1.0f;
        }
        covl[pi * 10 + pj] = cv;
    }
    __syncthreads();

    // ---- composite: thread = (channel c, pixel-quad pq -> rows 2pq, 2pq+1)
    {
        const int c  = tidb >> 2;
        const int pq = tidb & 3;
#pragma unroll
        for (int rr2 = 0; rr2 < 2; ++rr2) {
            const int prow = pq * 2 + rr2;
            float acc[8];
#pragma unroll
            for (int k = 0; k < 8; ++k) acc[k] = 0.0f;
#pragma unroll
            for (int k = 0; k < 8; ++k) {
                const int pxx = prow * 8 + k;
                const int n = nsl[pxx];
                for (int s = 0; s < n; ++s)
                    acc[k] = fmaf(wgt[s][pxx], F[wlp[s][pxx]][c], acc[k]);
            }
            float* op = out + (((size_t)(b * CC + c) << 14) | ((h0 + prow) << 7) | w0);
            *(float4*)op       = make_float4(acc[0], acc[1], acc[2], acc[3]);
            *(float4*)(op + 4) = make_float4(acc[4], acc[5], acc[6], acc[7]);
        }
    }

    // ---- bg: threads 0..63 dilate the 10x10 empty-patch
    if (tidb < 64) {
        const int prow = tidb >> 3, pcol = tidb & 7;
        float m = 0.0f;
#pragma unroll
        for (int di = 0; di < 3; ++di)
#pragma unroll
            for (int dj = 0; dj < 3; ++dj)
                m = fmaxf(m, covl[(prow + di) * 10 + (pcol + dj)]);
        bgout[(b << 14) | ((h0 + prow) << 7) | (w0 + pcol)] = (m > 0.0f) ? 1.0f : 0.0f;
    }
}

extern "C" void kernel_launch(void* const* d_in, const int* in_sizes, int n_in,
                              void* d_out, int out_size, void* d_ws, size_t ws_size,
                              hipStream_t stream) {
    const float* pts = (const float*)d_in[0];   // [B,P,3]
    const float* src = (const float*)d_in[1];   // [B,C,P]
    float* out = (float*)d_out;                 // [B,C,H,W] then bg [B,H,W]

    char* ws = (char*)d_ws;
    float* srcT  = (float*)ws;                                   // 2 MB
    int*   cnt   = (int*)(ws + (size_t)BB * PP * CC * 4);        // 2 KB
    int*   lists = cnt + NTILE;                                  // 192 KB

    hipMemsetAsync(cnt, 0, NTILE * sizeof(int), stream);
    prep_kernel<<<128, 256, 0, stream>>>(pts, src, srcT, cnt, lists);
    mega_kernel<<<NTILE, 256, 0, stream>>>(pts, srcT, cnt, lists,
                                           out, out + BB * CC * SZ * SZ);
}

// Round 8
// 27.083 us; speedup vs baseline: 1.7386x; 1.7386x over previous
//
#include <hip/hip_runtime.h>
#include <math.h>

#define BB 2
#define PP 4096
#define CC 64
#define SZ 128
#define KK 8

// radius = 1.5/128*2 = 0.0234375 (exact); r^2 = 9*2^-14 (exact)
#define R2f 0.00054931640625f
#define SLOTS 16          // per-pixel slot cap (Poisson mean 1.77; P(>=16) ~ 1e-9)
#define CG 16             // channels per composite thread (one cache line/slot)

typedef unsigned long long u64;
#define EMPTYK (~0ull)

// ---- Kernel 1: fused point-parallel exact binning + src transpose ----------
// 128 blocks x 256 threads. Bin: 4 threads/point (thread r = candidate row),
// bit-exact reference test, per-PIXEL slot lists of u64 (z_bits,idx) keys —
// unique totally-ordered keys make any atomic slot order deterministic.
// Transpose: [C][P] -> [P][C] via LDS 64x65 (R7-proven).
__global__ __launch_bounds__(256) void prep_kernel(const float* __restrict__ pts,
                                                   const float* __restrict__ src,
                                                   float* __restrict__ srcT,
                                                   int* __restrict__ cnt,
                                                   u64* __restrict__ keys) {
    const int tidb = threadIdx.x;
    const int blk  = blockIdx.x;               // 0..127

    // ---------------- bin ----------------
    {
        const int t  = blk * 256 + tidb;       // 0 .. BB*PP*4-1
        const int r  = t & 3;
        const int gp = t >> 2;                 // 0 .. BB*PP-1
        const int b  = gp >> 12;
        const int p  = gp & (PP - 1);
        const float px = pts[(size_t)gp * 3 + 0];
        const float py = pts[(size_t)gp * 3 + 1];
        const float pz = pts[(size_t)gp * 3 + 2];
        if (pz > 0.0f) {
            // gx(w) = 1-(2w+1)/128 equals -px at w = (1+px)*64 - 0.5
            const float u = (1.0f + px) * 64.0f - 0.5f;
            const float v = (1.0f + py) * 64.0f - 0.5f;
            const int wlo = max(0,   (int)ceilf (u - 1.53f));
            const int whi = min(127, (int)floorf(u + 1.53f));
            const int hlo = max(0,   (int)ceilf (v - 1.53f));
            const int hhi = min(127, (int)floorf(v + 1.53f));
            const int h = hlo + r;
            if (h <= hhi && wlo <= whi) {
                const float gy  = 1.0f - (2 * h + 1) * (1.0f / 128.0f);
                const float dy  = __fadd_rn(gy, py);         // ref: gy - (-py)
                const float dy2 = __fmul_rn(dy, dy);
                const u64 zkey = ((u64)__float_as_uint(pz) << 32) | (unsigned)p;
                for (int w = wlo; w <= whi; ++w) {
                    const float gx = 1.0f - (2 * w + 1) * (1.0f / 128.0f);
                    const float dx = __fadd_rn(gx, px);
                    const float d2 = __fadd_rn(__fmul_rn(dx, dx), dy2);
                    if (d2 < R2f) {
                        const int pix = (b << 14) | (h << 7) | w;
                        const int pos = atomicAdd(cnt + pix, 1);
                        if (pos < SLOTS) keys[pix * SLOTS + pos] = zkey;
                    }
                }
            }
        }
    }

    // ---------------- transpose ----------------
    __shared__ float lt[64][65];
    const int b2 = blk >> 6;
    const int p0 = (blk & 63) << 6;
    const int rr = tidb >> 6;                  // 0..3
    const int cc = tidb & 63;
#pragma unroll
    for (int k = 0; k < 16; ++k) {
        const int c = k * 4 + rr;
        lt[c][cc] = src[(size_t)((b2 * CC + c) << 12 | (p0 + cc))];
    }
    __syncthreads();
#pragma unroll
    for (int k = 0; k < 16; ++k) {
        const int pl = k * 4 + rr;
        srcT[(size_t)(((b2 << 12) | (p0 + pl)) << 6 | cc)] = lt[cc][pl];
    }
}

// ---- Kernel 2: fused select (8-deep K-buffer) + weights + composite + bg ---
// CG=16 channels/thread: per slot, features are one 64B line (4x float4).
__global__ __launch_bounds__(256) void selcomp_kernel(const float* __restrict__ pts,
                                                      const float* __restrict__ srcT,
                                                      const int* __restrict__ cnt,
                                                      const u64* __restrict__ keys,
                                                      float* __restrict__ out,
                                                      float* __restrict__ bgout) {
    const int t    = blockIdx.x * 256 + threadIdx.x;  // 0 .. BB*4*16384-1
    const int pix  = t & 16383;
    const int cg   = (t >> 14) & 3;                   // 4 groups of 16 channels
    const int b    = t >> 16;
    const int gpix = (b << 14) | pix;

    int n = cnt[gpix];
    n = (n > SLOTS) ? SLOTS : n;

    // K smallest (z, idx) via 8-deep sorted insertion on packed u64 keys.
    u64 kk[KK];
#pragma unroll
    for (int s = 0; s < KK; ++s) kk[s] = EMPTYK;
    for (int j = 0; j < n; ++j) {
        u64 kn = keys[gpix * SLOTS + j];
#pragma unroll
        for (int s = 0; s < KK; ++s) {
            if (kn < kk[s]) { u64 tk = kk[s]; kk[s] = kn; kn = tk; }
        }
    }

    const int w = pix & 127;
    const int h = pix >> 7;
    const float gx = 1.0f - (2 * w + 1) * (1.0f / 128.0f);
    const float gy = 1.0f - (2 * h + 1) * (1.0f / 128.0f);

    float acc[CG];
#pragma unroll
    for (int c = 0; c < CG; ++c) acc[c] = 0.0f;

    float T = 1.0f;
#pragma unroll
    for (int s = 0; s < KK; ++s) {
        if (kk[s] == EMPTYK) break;          // filled slots form a prefix
        const int id = (int)(kk[s] & 0xffffffffu);
        // recompute d2 bit-exactly (pts is L1/L2-resident, 96KB)
        const float* q = pts + (size_t)((b << 12) + id) * 3;
        const float dx = __fadd_rn(gx, q[0]);
        const float dy = __fadd_rn(gy, q[1]);
        const float d2 = __fadd_rn(__fmul_rn(dx, dx), __fmul_rn(dy, dy));
        float dn = d2 / R2f;
        dn = fminf(fmaxf(dn, 0.001f), 1.0f);
        const float a  = 1.0f - sqrtf(dn);
        const float wt = a * T;
        T = T * (1.0f - a);
        const float* fp = srcT + ((size_t)((b << 12) + id) << 6) + cg * CG;
#pragma unroll
        for (int v4 = 0; v4 < CG / 4; ++v4) {
            const float4 f = *(const float4*)(fp + v4 * 4);
            acc[v4 * 4 + 0] = fmaf(wt, f.x, acc[v4 * 4 + 0]);
            acc[v4 * 4 + 1] = fmaf(wt, f.y, acc[v4 * 4 + 1]);
            acc[v4 * 4 + 2] = fmaf(wt, f.z, acc[v4 * 4 + 2]);
            acc[v4 * 4 + 3] = fmaf(wt, f.w, acc[v4 * 4 + 3]);
        }
    }
#pragma unroll
    for (int c = 0; c < CG; ++c)
        out[((size_t)(b * CC + cg * CG + c) << 14) | pix] = acc[c];

    // background: dilate(cnt==0) over 3x3 — cg==0 threads handle their pixel
    if (cg == 0) {
        int bgv = 0;
#pragma unroll
        for (int dh = -1; dh <= 1; ++dh)
#pragma unroll
            for (int dw = -1; dw <= 1; ++dw) {
                const int hh = h + dh, ww = w + dw;
                if (hh >= 0 && hh < 128 && ww >= 0 && ww < 128)
                    if (cnt[(b << 14) | (hh << 7) | ww] == 0) bgv = 1;
            }
        bgout[gpix] = bgv ? 1.0f : 0.0f;
    }
}

extern "C" void kernel_launch(void* const* d_in, const int* in_sizes, int n_in,
                              void* d_out, int out_size, void* d_ws, size_t ws_size,
                              hipStream_t stream) {
    const float* pts = (const float*)d_in[0];   // [B,P,3]
    const float* src = (const float*)d_in[1];   // [B,C,P]
    float* out = (float*)d_out;                 // [B,C,H,W] then bg [B,H,W]

    const int npix = BB * SZ * SZ;              // 32768
    char* ws = (char*)d_ws;
    float* srcT = (float*)ws;                                  // 2 MB
    int*   cnt  = (int*)(ws + (size_t)BB * PP * CC * 4);       // 128 KB
    u64*   keys = (u64*)(ws + (size_t)BB * PP * CC * 4 + (size_t)npix * 4); // 4.2 MB

    hipMemsetAsync(cnt, 0, (size_t)npix * 4, stream);
    prep_kernel<<<128, 256, 0, stream>>>(pts, src, srcT, cnt, keys);
    selcomp_kernel<<<(BB * 4 * SZ * SZ) / 256, 256, 0, stream>>>(
        pts, srcT, cnt, keys, out, out + BB * CC * SZ * SZ);
}